// Round 13
// baseline (880.132 us; speedup 1.0000x reference)
//
#include <hip/hip_runtime.h>
#include <hip/hip_bf16.h>
#include <hip/hip_fp16.h>
#include <hip/hip_fp8.h>
#include <hip/hip_cooperative_groups.h>

namespace cg = cooperative_groups;

#define NN 50000
#define NE 800000
#define NG 64
#define DH 128

#define NPB 256                          // nodes per bucket
#define NBK ((NN + NPB - 1) / NPB)       // 196 buckets
#define EPB 4096                         // edges per partition block
#define NPBLK ((NE + EPB - 1) / EPB)     // 196
#define CAPB 5120                        // tmp slots per bucket
#define GEMMB 782                        // (50000/16+3)/4 virtual gemm blocks
#define CST 136                          // bf16 epilogue LDS row stride (ushorts)
#define CSTB 136                         // fp8 epilogue LDS row stride (bytes)
#define SMEM_BYTES 18432

#if defined(__has_builtin)
# if __has_builtin(__builtin_amdgcn_cvt_pk_f32_fp8) && __has_builtin(__builtin_amdgcn_cvt_pk_fp8_f32)
#  define HW_FP8 1
# endif
#endif

typedef __bf16 bfx8 __attribute__((ext_vector_type(8)));
typedef float  f32x4 __attribute__((ext_vector_type(4)));

__device__ __forceinline__ ushort f2b(float f) {        // fp32 -> bf16 RNE
    unsigned b = __float_as_uint(f);
    b += 0x7fff + ((b >> 16) & 1);
    return (ushort)(b >> 16);
}
__device__ __forceinline__ float b2f(ushort s) {
    return __uint_as_float((unsigned)s << 16);
}
__device__ __forceinline__ unsigned pk2(float a, float b) {
    return (unsigned)f2b(a) | ((unsigned)f2b(b) << 16);
}
__device__ __forceinline__ unsigned f2fp8(float v) {    // fp32 -> e4m3 (clamped)
    v = fminf(fmaxf(v, -448.f), 448.f);
#ifdef HW_FP8
    return (unsigned)__builtin_amdgcn_cvt_pk_fp8_f32(v, v, 0, false) & 0xFFu;
#else
    __hip_fp8_e4m3 t(v);
    return (unsigned)*(const unsigned char*)&t;
#endif
}
__device__ __forceinline__ void fp8x4_up(unsigned u, float* o) {
#ifdef HW_FP8
    auto lo = __builtin_amdgcn_cvt_pk_f32_fp8((int)u, false);
    auto hi = __builtin_amdgcn_cvt_pk_f32_fp8((int)u, true);
    o[0] = lo[0]; o[1] = lo[1]; o[2] = hi[0]; o[3] = hi[1];
#else
    #pragma unroll
    for (int k = 0; k < 4; ++k) {
        unsigned char c = (u >> (8 * k)) & 0xFF;
        o[k] = float(*(const __hip_fp8_e4m3*)&c);
    }
#endif
}

// =================== phase bodies (shared mega / fallback) ===================

// P0a: bin 4096 edges into fixed-capacity bucket regions
__device__ void part_body(char* smem, int vb, const int* __restrict__ ei,
                          int* __restrict__ gcur, unsigned* __restrict__ tmp) {
    int* cnt  = (int*)smem;
    int* base = cnt + NBK;
    int* lcur = base + NBK;
    int t = threadIdx.x;
    for (int i = t; i < NBK; i += 256) cnt[i] = 0;
    __syncthreads();
    int e0 = vb * EPB;
    int dreg[16];
    #pragma unroll
    for (int j = 0; j < 16; ++j) {
        int e = e0 + j * 256 + t;
        dreg[j] = (e < NE) ? ei[NE + e] : -1;
        if (e < NE) atomicAdd(&cnt[dreg[j] >> 8], 1);
    }
    __syncthreads();
    for (int i = t; i < NBK; i += 256) {
        base[i] = cnt[i] ? atomicAdd(&gcur[i], cnt[i]) : 0;
        lcur[i] = 0;
    }
    __syncthreads();
    #pragma unroll
    for (int j = 0; j < 16; ++j) {
        int e = e0 + j * 256 + t;
        if (e < NE) {
            int d = dreg[j], s = ei[e];
            int b = d >> 8;
            int r = atomicAdd(&lcur[b], 1);
            tmp[(size_t)b * CAPB + base[b] + r] = ((unsigned)(d & 255) << 16) | (unsigned)s;
        }
    }
}

// P0b: weight transpose/convert -> Wt[n][k] bf16
__device__ void wt_body(int vb, const float* __restrict__ W0,
                        const float* __restrict__ Wc, ushort* __restrict__ Wt) {
    int i = vb * 256 + threadIdx.x;              // 0 .. 65535
    int m = i >> 14;
    int r = i & 16383;
    int k = r >> 7, n = r & 127;
    const float* src = (m == 0) ? W0 : (Wc + (size_t)(m - 1) * DH * DH);
    Wt[(size_t)m * DH * DH + n * DH + k] = f2b(src[r]);
}

// P1a: per-bucket degree count + local padded offsets
__device__ void bcount_body(char* smem, int b, const unsigned* __restrict__ tmp,
                            const int* __restrict__ gcur, int* __restrict__ deg,
                            int* __restrict__ ploc, int* __restrict__ bsizeP) {
    int* dcnt = (int*)smem;                      // NPB ints
    int* wsum = dcnt + NPB;                      // 4 ints
    int t = threadIdx.x;
    dcnt[t] = 0;
    __syncthreads();
    int ne = gcur[b];
    for (int e = t; e < ne; e += 256)
        atomicAdd(&dcnt[tmp[(size_t)b * CAPB + e] >> 16], 1);
    __syncthreads();
    int n = b * NPB + t;
    int d = (n < NN) ? dcnt[t] : 0;
    int p = (n < NN) ? ((d + 4) & ~3) : 0;       // align4(deg+1)
    int inc = p;
    #pragma unroll
    for (int off = 1; off < 64; off <<= 1) {
        int u = __shfl_up(inc, off);
        if ((t & 63) >= off) inc += u;
    }
    if ((t & 63) == 63) wsum[t >> 6] = inc;
    __syncthreads();
    int w = t >> 6, woff = 0;
    #pragma unroll
    for (int k = 0; k < 4; ++k) if (k < w) woff += wsum[k];
    int lofs = inc - p + woff;
    if (n < NN) { deg[n] = d; ploc[n] = lofs; }
    if (t == 255) bsizeP[b] = lofs + p;
}

// MFMA GEMM: one wave per 16 rows. D: col=lane&15, row=quad*4+reg.
template<bool AF32, bool DOTS, bool OUTFP8>
__device__ void gemm_body(char* smem, int gblk,
        const void* __restrict__ Av, const ushort* __restrict__ Wt,
        const float* __restrict__ bias, void* __restrict__ C, int relu,
        const float* __restrict__ avs, const float* __restrict__ avd,
        float* __restrict__ asrc, float* __restrict__ adst) {
    int tid = threadIdx.x;
    int wid = (gblk * 256 + tid) >> 6;
    int lane = tid & 63;
    int row0 = wid * 16;
    if (row0 >= NN) return;
    int mrow = lane & 15;
    int quad = lane >> 4;
    int arow = row0 + mrow;

    f32x4 acc[8];
    #pragma unroll
    for (int t = 0; t < 8; ++t)
        #pragma unroll
        for (int r = 0; r < 4; ++r) acc[t][r] = 0.f;

    #pragma unroll
    for (int ks = 0; ks < 4; ++ks) {
        int k0 = ks * 32 + quad * 8;
        bfx8 a;
        if (AF32) {
            const float* ap = (const float*)Av + (size_t)arow * DH + k0;
            union { ushort s[8]; bfx8 v; } u;
            #pragma unroll
            for (int j = 0; j < 8; ++j) u.s[j] = f2b(ap[j]);
            a = u.v;
        } else {
            a = *(const bfx8*)((const ushort*)Av + (size_t)arow * DH + k0);
        }
        #pragma unroll
        for (int t = 0; t < 8; ++t) {
            bfx8 b = *(const bfx8*)(Wt + (size_t)(t * 16 + mrow) * DH + k0);
            acc[t] = __builtin_amdgcn_mfma_f32_16x16x32_bf16(a, b, acc[t], 0, 0, 0);
        }
    }

    if (OUTFP8) {
        uchar* my = (uchar*)smem + (tid >> 6) * 16 * CSTB;
        #pragma unroll
        for (int t = 0; t < 8; ++t) {
            int col = t * 16 + mrow;
            float bv = bias ? bias[col] : 0.f;
            #pragma unroll
            for (int r = 0; r < 4; ++r) {
                float v = acc[t][r] + bv;
                if (relu) v = fmaxf(v, 0.f);
                my[(quad * 4 + r) * CSTB + col] = (uchar)f2fp8(v);
            }
        }
        #pragma unroll
        for (int i = 0; i < 4; ++i) {
            int idx = i * 64 + lane;
            int row = idx >> 4;
            int c8 = idx & 15;
            uint2 u = *(const uint2*)(my + row * CSTB + c8 * 8);
            *(uint2*)((uchar*)C + (size_t)(row0 + row) * DH + c8 * 8) = u;
        }
    } else {
        ushort* my = (ushort*)smem + (tid >> 6) * 16 * CST;
        #pragma unroll
        for (int t = 0; t < 8; ++t) {
            int col = t * 16 + mrow;
            float bv = bias ? bias[col] : 0.f;
            #pragma unroll
            for (int r = 0; r < 4; ++r) {
                float v = acc[t][r] + bv;
                if (relu) v = fmaxf(v, 0.f);
                my[(quad * 4 + r) * CST + col] = f2b(v);
            }
        }
        #pragma unroll
        for (int i = 0; i < 4; ++i) {
            int idx = i * 64 + lane;
            int row = idx >> 4;
            int c16 = idx & 15;
            uint4 u = *(const uint4*)(my + row * CST + c16 * 8);
            *(uint4*)((ushort*)C + (size_t)(row0 + row) * DH + c16 * 8) = u;
        }
    }

    if (DOTS) {
        float av[8], dv[8];
        #pragma unroll
        for (int t = 0; t < 8; ++t) {
            av[t] = avs[t * 16 + mrow];
            dv[t] = avd[t * 16 + mrow];
        }
        int orow = row0 + quad * 4;
        #pragma unroll
        for (int r = 0; r < 4; ++r) {
            float ps = 0.f, pd = 0.f;
            #pragma unroll
            for (int t = 0; t < 8; ++t) {
                ps += acc[t][r] * av[t];
                pd += acc[t][r] * dv[t];
            }
            #pragma unroll
            for (int off = 1; off < 16; off <<= 1) {
                ps += __shfl_xor(ps, off);
                pd += __shfl_xor(pd, off);
            }
            if (mrow == 0) {
                asrc[orow + r] = ps;
                adst[orow + r] = pd;
            }
        }
    }
}

// P2a: assemble csr per bucket (LDS-staged, sequential writes)
__device__ void build_body(char* smem, int b, const unsigned* __restrict__ tmp,
                           const int* __restrict__ gcur, const int* __restrict__ bsizeP,
                           const int* __restrict__ ploc, int* __restrict__ pstart,
                           ushort* __restrict__ csr) {
    ushort* buf = (ushort*)smem;                  // 8192 ushorts
    int* lcur = (int*)(smem + 16384);             // NPB ints
    int* sm   = (int*)(smem + 16384 + 1024);      // 256 ints (scan)
    int t = threadIdx.x;
    int v = (t < NBK) ? bsizeP[t] : 0;
    sm[t] = v;
    __syncthreads();
    for (int off = 1; off < 256; off <<= 1) {
        int u = (t >= off) ? sm[t - off] : 0;
        __syncthreads();
        sm[t] += u;
        __syncthreads();
    }
    int r0 = sm[b] - bsizeP[b];
    int S = bsizeP[b];                            // multiple of 4
    int n0 = b * NPB, n1 = min(n0 + NPB, NN), nodes = n1 - n0;
    int ne = gcur[b];

    if (S <= 8192) {
        for (int i = t; i < (S >> 1); i += 256) ((unsigned*)buf)[i] = 0;
        __syncthreads();
        if (t < nodes) {
            int lp = ploc[n0 + t];
            pstart[n0 + t] = r0 + lp;
            lcur[t] = lp + 1;
            buf[lp] = (ushort)(n0 + t);           // self-loop first
        }
        __syncthreads();
        for (int e = t; e < ne; e += 256) {
            unsigned u = tmp[(size_t)b * CAPB + e];
            int slot = atomicAdd(&lcur[u >> 16], 1);
            buf[slot] = (ushort)(u & 0xffffu);
        }
        __syncthreads();
        unsigned* dst = (unsigned*)(csr + r0);
        for (int i = t; i < (S >> 1); i += 256) dst[i] = ((unsigned*)buf)[i];
    } else {
        for (int i = t; i < S; i += 256) csr[r0 + i] = 0;
        __syncthreads();
        if (t < nodes) {
            int lp = ploc[n0 + t];
            pstart[n0 + t] = r0 + lp;
            lcur[t] = r0 + lp + 1;
            csr[r0 + lp] = (ushort)(n0 + t);
        }
        __syncthreads();
        for (int e = t; e < ne; e += 256) {
            unsigned u = tmp[(size_t)b * CAPB + e];
            int slot = atomicAdd(&lcur[u >> 16], 1);
            csr[slot] = (ushort)(u & 0xffffu);
        }
    }
}

// aggr: one wave per node (fp8 h rows, padded x4 segments)
__device__ void aggr_wave(int wid, int lane, const uchar* __restrict__ h8,
                          const float* __restrict__ asrc, const float* __restrict__ adst,
                          const int* __restrict__ pstart, const int* __restrict__ deg,
                          const ushort* __restrict__ csr, const float* __restrict__ bias,
                          ushort* __restrict__ hout) {
    int start = pstart[wid];
    int cnt = deg[wid] + 1;
    float ad = adst[wid];

    if (cnt <= 64) {
        int s = csr[start + lane];               // pads are 0 (valid index)
        float e = -1e30f;
        if (lane < cnt) {
            float t = asrc[s] + ad;
            e = fmaxf(t, 0.f) + 0.2f * fminf(t, 0.f);
        }
        float m = e;
        #pragma unroll
        for (int off = 32; off; off >>= 1) m = fmaxf(m, __shfl_xor(m, off));
        float w = (lane < cnt) ? __expf(e - m) : 0.f;
        float dsum = w;
        #pragma unroll
        for (int off = 32; off; off >>= 1) dsum += __shfl_xor(dsum, off);

        int g = lane >> 4, fidx = lane & 15;
        float acc[8];
        #pragma unroll
        for (int k = 0; k < 8; ++k) acc[k] = 0.f;

        int steps = (cnt + 3) >> 2;
        const uint2* hp = (const uint2*)h8;
        int j = 0;
        for (; j + 3 < steps; j += 4) {
            int   e0 = j * 4 + g,      e1 = e0 + 4,  e2 = e0 + 8,  e3 = e0 + 12;
            float w0 = __shfl(w, e0),  w1 = __shfl(w, e1);
            float w2 = __shfl(w, e2),  w3 = __shfl(w, e3);
            int   s0 = __shfl(s, e0),  s1 = __shfl(s, e1);
            int   s2 = __shfl(s, e2),  s3 = __shfl(s, e3);
            uint2 u0 = hp[(size_t)s0 * 16 + fidx];
            uint2 u1 = hp[(size_t)s1 * 16 + fidx];
            uint2 u2 = hp[(size_t)s2 * 16 + fidx];
            uint2 u3 = hp[(size_t)s3 * 16 + fidx];
            float v[8];
            fp8x4_up(u0.x, v); fp8x4_up(u0.y, v + 4);
            #pragma unroll
            for (int k = 0; k < 8; ++k) acc[k] += w0 * v[k];
            fp8x4_up(u1.x, v); fp8x4_up(u1.y, v + 4);
            #pragma unroll
            for (int k = 0; k < 8; ++k) acc[k] += w1 * v[k];
            fp8x4_up(u2.x, v); fp8x4_up(u2.y, v + 4);
            #pragma unroll
            for (int k = 0; k < 8; ++k) acc[k] += w2 * v[k];
            fp8x4_up(u3.x, v); fp8x4_up(u3.y, v + 4);
            #pragma unroll
            for (int k = 0; k < 8; ++k) acc[k] += w3 * v[k];
        }
        for (; j < steps; ++j) {
            int e0 = j * 4 + g;
            float w0 = __shfl(w, e0);
            int   s0 = __shfl(s, e0);
            uint2 u0 = hp[(size_t)s0 * 16 + fidx];
            float v[8];
            fp8x4_up(u0.x, v); fp8x4_up(u0.y, v + 4);
            #pragma unroll
            for (int k = 0; k < 8; ++k) acc[k] += w0 * v[k];
        }
        #pragma unroll
        for (int k = 0; k < 8; ++k) {
            acc[k] += __shfl_xor(acc[k], 16);
            acc[k] += __shfl_xor(acc[k], 32);
        }
        if (g == 0) {
            float inv = 1.f / (dsum + 1e-16f);
            const float4* bp = (const float4*)bias;
            float4 b0 = bp[fidx * 2], b1 = bp[fidx * 2 + 1];
            uint4 o;
            o.x = pk2(fmaxf(acc[0] * inv + b0.x, 0.f), fmaxf(acc[1] * inv + b0.y, 0.f));
            o.y = pk2(fmaxf(acc[2] * inv + b0.z, 0.f), fmaxf(acc[3] * inv + b0.w, 0.f));
            o.z = pk2(fmaxf(acc[4] * inv + b1.x, 0.f), fmaxf(acc[5] * inv + b1.y, 0.f));
            o.w = pk2(fmaxf(acc[6] * inv + b1.z, 0.f), fmaxf(acc[7] * inv + b1.w, 0.f));
            ((uint4*)hout)[(size_t)wid * 16 + fidx] = o;
        }
        return;
    }

    // generic fallback (deg > 64) — never with this data
    float m = -1e30f;
    for (int i0 = start; i0 < start + cnt; i0 += 64) {
        int i = i0 + lane;
        float e = -1e30f;
        if (i < start + cnt) {
            int s = csr[i];
            float t = asrc[s] + ad;
            e = fmaxf(t, 0.f) + 0.2f * fminf(t, 0.f);
        }
        m = fmaxf(m, e);
    }
    #pragma unroll
    for (int off = 32; off; off >>= 1) m = fmaxf(m, __shfl_xor(m, off));

    float accx = 0.f, accy = 0.f, dsum = 0.f;
    for (int i0 = start; i0 < start + cnt; i0 += 64) {
        int i = i0 + lane;
        int s = 0; float w = 0.f;
        if (i < start + cnt) {
            s = csr[i];
            float t = asrc[s] + ad;
            float e = fmaxf(t, 0.f) + 0.2f * fminf(t, 0.f);
            w = __expf(e - m);
        }
        dsum += w;
        int cl = min(64, start + cnt - i0);
        for (int j = 0; j < cl; ++j) {
            int   sj = __shfl(s, j);
            float wj = __shfl(w, j);
            unsigned us = *(const ushort*)(h8 + (size_t)sj * DH + lane * 2);
            float v[4];
            fp8x4_up(us, v);
            accx += wj * v[0];
            accy += wj * v[1];
        }
    }
    #pragma unroll
    for (int off = 32; off; off >>= 1) dsum += __shfl_xor(dsum, off);

    float inv = 1.f / (dsum + 1e-16f);
    float ox = fmaxf(accx * inv + bias[lane * 2], 0.f);
    float oy = fmaxf(accy * inv + bias[lane * 2 + 1], 0.f);
    *(unsigned*)(hout + (size_t)wid * DH + lane * 2) = pk2(ox, oy);
}

// pool: per 64-node tile, 2 rows in flight
__device__ void pool_body(int vb, const ushort* __restrict__ h,
                          const int* __restrict__ batch, float* __restrict__ gsum,
                          int* __restrict__ gcnt) {
    int slot = threadIdx.x >> 7;
    int f = threadIdx.x & 127;
    int n0 = vb * 64;
    int n1 = min(n0 + 64, NN);
    int first = n0 + slot;
    if (first >= n1) return;
    int g0 = batch[n0], g1 = batch[n1 - 1];
    if (g0 == g1) {
        float acc = 0.f;
        for (int nd = first; nd < n1; nd += 2)
            acc += b2f(h[(size_t)nd * DH + f]);
        atomicAdd(&gsum[g0 * DH + f], acc);
        if (f == 0 && slot == 0) atomicAdd(&gcnt[g0], n1 - n0);
        return;
    }
    float acc = 0.f; int run = 0;
    int gcur = batch[first];
    for (int nd = first; nd < n1; nd += 2) {
        int g = batch[nd];
        if (g != gcur) {
            atomicAdd(&gsum[gcur * DH + f], acc);
            if (f == 0) atomicAdd(&gcnt[gcur], run);
            acc = 0.f; run = 0; gcur = g;
        }
        acc += b2f(h[(size_t)nd * DH + f]);
        run += 1;
    }
    atomicAdd(&gsum[gcur * DH + f], acc);
    if (f == 0) atomicAdd(&gcnt[gcur], run);
}

__device__ void final_body(const float* __restrict__ gsum, const int* __restrict__ gcnt,
                           const float* __restrict__ W1, const float* __restrict__ b1,
                           float* __restrict__ out) {
    for (int t = threadIdx.x; t < NG * 10; t += 256) {
        int g = t / 10, o = t % 10;
        float inv = 1.f / fmaxf((float)gcnt[g], 1.f);
        float acc = 0.f;
        for (int f = 0; f < DH; ++f) acc += gsum[g * DH + f] * W1[f * 10 + o];
        out[t] = acc * inv + b1[o];
    }
}

// =================== cooperative mega-kernel ===================
__launch_bounds__(256)
__global__ void k_mega(const int* ei, const float* x, const float* W0, const float* Wc,
                       const float* b0, const float* att_src, const float* att_dst,
                       const float* bc, const float* W1, const float* b1,
                       const int* batch, float* out,
                       uchar* hA, ushort* hB, ushort* Wt, int* pstart, ushort* csr,
                       unsigned* tmp, float* asrc, float* adst, int* deg, int* ploc,
                       int* gcur, int* bsizeP, float* gsum, int* gcnt) {
    cg::grid_group grid = cg::this_grid();
    __shared__ char smem[SMEM_BYTES];
    int nb = gridDim.x;
    int lane = threadIdx.x & 63;
    int gw = (blockIdx.x * 256 + threadIdx.x) >> 6;
    int wstride = nb * 4;

    // P0: edge partition + weight prep
    for (int vb = blockIdx.x; vb < NPBLK + 256; vb += nb) {
        __syncthreads();
        if (vb < NPBLK) part_body(smem, vb, ei, gcur, tmp);
        else            wt_body(vb - NPBLK, W0, Wc, Wt);
    }
    grid.sync();

    // P1: bucket degree counts + GEMM-1 (x @ W0 -> hB bf16)
    for (int vb = blockIdx.x; vb < NBK + GEMMB; vb += nb) {
        __syncthreads();
        if (vb < NBK) bcount_body(smem, vb, tmp, gcur, deg, ploc, bsizeP);
        else gemm_body<true, false, false>(smem, vb - NBK, x, Wt, b0, hB, 1,
                                           nullptr, nullptr, nullptr, nullptr);
    }
    grid.sync();

    // P2..P7: per layer: gemmdots (+ build csr in l=0) then aggr
    for (int l = 0; l < 3; ++l) {
        int extra = (l == 0) ? NBK : 0;
        const ushort* Wl = Wt + (size_t)(l + 1) * DH * DH;
        for (int vb = blockIdx.x; vb < GEMMB + extra; vb += nb) {
            __syncthreads();
            if (vb < extra) build_body(smem, vb, tmp, gcur, bsizeP, ploc, pstart, csr);
            else gemm_body<false, true, true>(smem, vb - extra, hB, Wl, nullptr, hA, 0,
                                              att_src + l * DH, att_dst + l * DH,
                                              asrc, adst);
        }
        grid.sync();
        for (int wid = gw; wid < NN; wid += wstride)
            aggr_wave(wid, lane, hA, asrc, adst, pstart, deg, csr, bc + l * DH, hB);
        grid.sync();
    }

    // P8: pool
    for (int vb = blockIdx.x; vb < (NN + 63) / 64; vb += nb)
        pool_body(vb, hB, batch, gsum, gcnt);
    grid.sync();

    // P9: final
    if (blockIdx.x == 0) final_body(gsum, gcnt, W1, b1, out);
}

// =================== fallback (non-cooperative) kernels ===================
__launch_bounds__(256)
__global__ void k_partwt(const int* ei, int* gcur, unsigned* tmp,
                         const float* W0, const float* Wc, ushort* Wt) {
    __shared__ char smem[SMEM_BYTES];
    if (blockIdx.x < NPBLK) part_body(smem, blockIdx.x, ei, gcur, tmp);
    else                    wt_body(blockIdx.x - NPBLK, W0, Wc, Wt);
}
__launch_bounds__(256)
__global__ void k_bcount(const unsigned* tmp, const int* gcur, int* deg,
                         int* ploc, int* bsizeP) {
    __shared__ char smem[SMEM_BYTES];
    bcount_body(smem, blockIdx.x, tmp, gcur, deg, ploc, bsizeP);
}
__launch_bounds__(256)
__global__ void k_buildgemm(const unsigned* tmp, const int* gcur, const int* bsizeP,
                            const int* ploc, int* pstart, ushort* csr,
                            const float* x, const ushort* Wt, const float* b0,
                            ushort* hB) {
    __shared__ char smem[SMEM_BYTES];
    if (blockIdx.x < GEMMB)
        gemm_body<true, false, false>(smem, blockIdx.x, x, Wt, b0, hB, 1,
                                      nullptr, nullptr, nullptr, nullptr);
    else
        build_body(smem, blockIdx.x - GEMMB, tmp, gcur, bsizeP, ploc, pstart, csr);
}
__launch_bounds__(256)
__global__ void k_gemmdots(const ushort* hB, const ushort* Wt, uchar* hA,
                           const float* avs, const float* avd,
                           float* asrc, float* adst) {
    __shared__ char smem[SMEM_BYTES];
    gemm_body<false, true, true>(smem, blockIdx.x, hB, Wt, nullptr, hA, 0,
                                 avs, avd, asrc, adst);
}
__launch_bounds__(256)
__global__ void k_aggr(const uchar* h8, const float* asrc, const float* adst,
                       const int* pstart, const int* deg, const ushort* csr,
                       const float* bias, ushort* hout) {
    int wid = (blockIdx.x * blockDim.x + threadIdx.x) >> 6;
    if (wid >= NN) return;
    aggr_wave(wid, threadIdx.x & 63, h8, asrc, adst, pstart, deg, csr, bias, hout);
}
__launch_bounds__(256)
__global__ void k_pool(const ushort* h, const int* batch, float* gsum, int* gcnt) {
    pool_body(blockIdx.x, h, batch, gsum, gcnt);
}
__global__ void k_final(const float* gsum, const int* gcnt, const float* W1,
                        const float* b1, float* out) {
    final_body(gsum, gcnt, W1, b1, out);
}

extern "C" void kernel_launch(void* const* d_in, const int* in_sizes, int n_in,
                              void* d_out, int out_size, void* d_ws, size_t ws_size,
                              hipStream_t stream) {
    const float* x       = (const float*)d_in[0];
    const int*   ei      = (const int*)d_in[1];
    const int*   batch   = (const int*)d_in[3];
    const float* W0      = (const float*)d_in[4];
    const float* b0      = (const float*)d_in[5];
    const float* Wc      = (const float*)d_in[6];
    const float* att_src = (const float*)d_in[7];
    const float* att_dst = (const float*)d_in[8];
    const float* bc      = (const float*)d_in[9];
    const float* W1      = (const float*)d_in[10];
    const float* b1      = (const float*)d_in[11];
    float* out = (float*)d_out;

    char* ws = (char*)d_ws;
    size_t off = 0;
    auto alloc = [&](size_t bytes) {
        void* p = ws + off;
        off += (bytes + 255) & ~(size_t)255;
        return p;
    };
    uchar*    hA     = (uchar*)alloc((size_t)NN * DH);        // fp8 e4m3
    ushort*   hB     = (ushort*)alloc((size_t)NN * DH * 2);   // bf16
    ushort*   Wt     = (ushort*)alloc((size_t)4 * DH * DH * 2);
    int*      pstart = (int*)alloc((size_t)NN * 4);
    ushort*   csr    = (ushort*)alloc((size_t)(NE + 4 * NN + 64) * 2);
    unsigned* tmp    = (unsigned*)alloc((size_t)NBK * CAPB * 4);
    float*    asrc   = (float*)alloc(NN * 4);
    float*    adst   = (float*)alloc(NN * 4);
    int*      deg    = (int*)alloc(NN * 4);
    int*      ploc   = (int*)alloc(NN * 4);
    int*      gcur   = (int*)alloc((NBK + 1) * 4);
    int*      bsizeP = (int*)alloc((NBK + 1) * 4);
    float*    gsum   = (float*)alloc(NG * DH * 4);   // gsum+gcnt adjacent
    int*      gcnt   = (int*)alloc(NG * 4);

    hipMemsetAsync(gcur, 0, (NBK + 1) * 4, stream);
    hipMemsetAsync(gsum, 0, NG * DH * 4 + 256, stream);  // covers gcnt too

    // grid sized for guaranteed co-residency (cooperative requirement)
    int maxPerCU = 0;
    hipError_t occ = hipOccupancyMaxActiveBlocksPerMultiprocessor(
        &maxPerCU, (const void*)k_mega, 256, 0);
    bool coop_ok = (occ == hipSuccess) && (maxPerCU >= 1);
    hipError_t lerr = hipErrorUnknown;
    if (coop_ok) {
        int grid = maxPerCU * 256;
        if (grid > 2048) grid = 2048;
        void* kargs[] = {
            (void*)&ei, (void*)&x, (void*)&W0, (void*)&Wc, (void*)&b0,
            (void*)&att_src, (void*)&att_dst, (void*)&bc, (void*)&W1, (void*)&b1,
            (void*)&batch, (void*)&out, (void*)&hA, (void*)&hB, (void*)&Wt,
            (void*)&pstart, (void*)&csr, (void*)&tmp, (void*)&asrc, (void*)&adst,
            (void*)&deg, (void*)&ploc, (void*)&gcur, (void*)&bsizeP, (void*)&gsum,
            (void*)&gcnt };
        lerr = hipLaunchCooperativeKernel((const void*)k_mega, dim3(grid), dim3(256),
                                          kargs, 0, stream);
    }
    if (lerr != hipSuccess) {
        // fallback: proven multi-kernel path
        k_partwt<<<NPBLK + 256, 256, 0, stream>>>(ei, gcur, tmp, W0, Wc, Wt);
        k_bcount<<<NBK, 256, 0, stream>>>(tmp, gcur, deg, ploc, bsizeP);
        k_buildgemm<<<GEMMB + NBK, 256, 0, stream>>>(tmp, gcur, bsizeP, ploc, pstart,
                                                     csr, x, Wt, b0, hB);
        for (int l = 0; l < 3; ++l) {
            k_gemmdots<<<GEMMB, 256, 0, stream>>>(hB, Wt + (size_t)(l + 1) * DH * DH,
                                                  hA, att_src + l * DH,
                                                  att_dst + l * DH, asrc, adst);
            k_aggr<<<(NN + 3) / 4, 256, 0, stream>>>(hA, asrc, adst, pstart, deg, csr,
                                                     bc + l * DH, hB);
        }
        k_pool<<<(NN + 63) / 64, 256, 0, stream>>>(hB, batch, gsum, gcnt);
        k_final<<<1, NG * 10, 0, stream>>>(gsum, gcnt, W1, b1, out);
    }
}

// Round 14
// 326.636 us; speedup vs baseline: 2.6945x; 2.6945x over previous
//
#include <hip/hip_runtime.h>
#include <hip/hip_bf16.h>
#include <hip/hip_fp16.h>
#include <hip/hip_fp8.h>

#define NN 50000
#define NE 800000
#define NG 64
#define DH 128

#define NPB 256                          // nodes per bucket
#define NBK ((NN + NPB - 1) / NPB)       // 196 buckets
#define EPB 4096                         // edges per partition block
#define NPBLK ((NE + EPB - 1) / EPB)     // 196
#define CAPB 5120                        // tmp slots per bucket
#define GEMMB 782                        // (50000/16+3)/4 blocks of 4 waves
#define CST 136                          // bf16 epilogue LDS row stride (ushorts)
#define CSTB 136                         // fp8 epilogue LDS row stride (bytes)
#define SMEM_BYTES 18432                 // max(gemm 17408, build 16384+1024+1024)

#if defined(__has_builtin)
# if __has_builtin(__builtin_amdgcn_cvt_pk_f32_fp8) && __has_builtin(__builtin_amdgcn_cvt_pk_fp8_f32)
#  define HW_FP8 1
# endif
#endif

typedef __bf16 bfx8 __attribute__((ext_vector_type(8)));
typedef float  f32x4 __attribute__((ext_vector_type(4)));

__device__ __forceinline__ ushort f2b(float f) {        // fp32 -> bf16 RNE
    unsigned b = __float_as_uint(f);
    b += 0x7fff + ((b >> 16) & 1);
    return (ushort)(b >> 16);
}
__device__ __forceinline__ float b2f(ushort s) {
    return __uint_as_float((unsigned)s << 16);
}
__device__ __forceinline__ unsigned pk2(float a, float b) {
    return (unsigned)f2b(a) | ((unsigned)f2b(b) << 16);
}
__device__ __forceinline__ unsigned f2fp8(float v) {    // fp32 -> e4m3 (clamped)
    v = fminf(fmaxf(v, -448.f), 448.f);
#ifdef HW_FP8
    return (unsigned)__builtin_amdgcn_cvt_pk_fp8_f32(v, v, 0, false) & 0xFFu;
#else
    __hip_fp8_e4m3 t(v);
    return (unsigned)*(const unsigned char*)&t;
#endif
}
__device__ __forceinline__ void fp8x4_up(unsigned u, float* o) {
#ifdef HW_FP8
    auto lo = __builtin_amdgcn_cvt_pk_f32_fp8((int)u, false);
    auto hi = __builtin_amdgcn_cvt_pk_f32_fp8((int)u, true);
    o[0] = lo[0]; o[1] = lo[1]; o[2] = hi[0]; o[3] = hi[1];
#else
    #pragma unroll
    for (int k = 0; k < 4; ++k) {
        unsigned char c = (u >> (8 * k)) & 0xFF;
        o[k] = float(*(const __hip_fp8_e4m3*)&c);
    }
#endif
}

// ---------------- partition edges into dst-buckets (+ fused weight prep) ----
__launch_bounds__(256)
__global__ void k_partwt(const int* __restrict__ ei, int* __restrict__ gcur,
                         unsigned* __restrict__ tmp,
                         const float* __restrict__ W0, const float* __restrict__ Wc,
                         ushort* __restrict__ Wt) {
    int t = threadIdx.x;
    if (blockIdx.x >= NPBLK) {
        int i = (blockIdx.x - NPBLK) * 256 + t;      // 0 .. 65535
        int m = i >> 14;
        int r = i & 16383;
        int k = r >> 7, n = r & 127;
        const float* src = (m == 0) ? W0 : (Wc + (size_t)(m - 1) * DH * DH);
        Wt[(size_t)m * DH * DH + n * DH + k] = f2b(src[r]);
        return;
    }
    __shared__ int cnt[NBK], base[NBK], lcur[NBK];
    for (int i = t; i < NBK; i += 256) cnt[i] = 0;
    __syncthreads();
    int e0 = blockIdx.x * EPB;
    int dreg[16];
    #pragma unroll
    for (int j = 0; j < 16; ++j) {
        int e = e0 + j * 256 + t;
        dreg[j] = (e < NE) ? ei[NE + e] : -1;
        if (e < NE) atomicAdd(&cnt[dreg[j] >> 8], 1);
    }
    __syncthreads();
    for (int i = t; i < NBK; i += 256) {
        base[i] = cnt[i] ? atomicAdd(&gcur[i], cnt[i]) : 0;
        lcur[i] = 0;
    }
    __syncthreads();
    #pragma unroll
    for (int j = 0; j < 16; ++j) {
        int e = e0 + j * 256 + t;
        if (e < NE) {
            int d = dreg[j], s = ei[e];
            int b = d >> 8;
            int r = atomicAdd(&lcur[b], 1);
            tmp[(size_t)b * CAPB + base[b] + r] = ((unsigned)(d & 255) << 16) | (unsigned)s;
        }
    }
}

// ---------------- per-bucket degree count + local padded offsets ----------
__launch_bounds__(256)
__global__ void k_bcount(const unsigned* __restrict__ tmp, const int* __restrict__ gcur,
                         int* __restrict__ deg, int* __restrict__ ploc,
                         int* __restrict__ bsizeP) {
    __shared__ int dcnt[NPB];
    int b = blockIdx.x, t = threadIdx.x;
    dcnt[t] = 0;
    __syncthreads();
    int ne = gcur[b];
    for (int e = t; e < ne; e += 256)
        atomicAdd(&dcnt[tmp[(size_t)b * CAPB + e] >> 16], 1);
    __syncthreads();
    int n = b * NPB + t;
    int d = (n < NN) ? dcnt[t] : 0;
    int p = (n < NN) ? ((d + 4) & ~3) : 0;           // align4(deg+1)
    int inc = p;
    #pragma unroll
    for (int off = 1; off < 64; off <<= 1) {
        int u = __shfl_up(inc, off);
        if ((t & 63) >= off) inc += u;
    }
    __shared__ int wsum[4];
    if ((t & 63) == 63) wsum[t >> 6] = inc;
    __syncthreads();
    int w = t >> 6, woff = 0;
    #pragma unroll
    for (int k = 0; k < 4; ++k) if (k < w) woff += wsum[k];
    int lofs = inc - p + woff;
    if (n < NN) { deg[n] = d; ploc[n] = lofs; }
    if (t == 255) bsizeP[b] = lofs + p;              // bucket padded total
}

// ---------------- MFMA GEMM body (shared) ----------------
// One wave per 16 rows. D: col=lane&15, row=quad*4+reg (verified m89).
// OUTFP8: write e4m3 bytes (aggr gather input) else bf16 (next GEMM / pool).
template<bool AF32, bool DOTS, bool OUTFP8>
__device__ __forceinline__ void gemm_body(char* smem, int gblk,
        const void* __restrict__ Av, const ushort* __restrict__ Wt,
        const float* __restrict__ bias, void* __restrict__ C, int relu,
        const float* __restrict__ avs, const float* __restrict__ avd,
        float* __restrict__ asrc, float* __restrict__ adst) {
    int tid = threadIdx.x;
    int wid = (gblk * 256 + tid) >> 6;
    int lane = tid & 63;
    int row0 = wid * 16;
    if (row0 >= NN) return;
    int mrow = lane & 15;
    int quad = lane >> 4;
    int arow = row0 + mrow;

    f32x4 acc[8];
    #pragma unroll
    for (int t = 0; t < 8; ++t)
        #pragma unroll
        for (int r = 0; r < 4; ++r) acc[t][r] = 0.f;

    #pragma unroll
    for (int ks = 0; ks < 4; ++ks) {
        int k0 = ks * 32 + quad * 8;
        bfx8 a;
        if (AF32) {
            const float* ap = (const float*)Av + (size_t)arow * DH + k0;
            union { ushort s[8]; bfx8 v; } u;
            #pragma unroll
            for (int j = 0; j < 8; ++j) u.s[j] = f2b(ap[j]);
            a = u.v;
        } else {
            a = *(const bfx8*)((const ushort*)Av + (size_t)arow * DH + k0);
        }
        #pragma unroll
        for (int t = 0; t < 8; ++t) {
            bfx8 b = *(const bfx8*)(Wt + (size_t)(t * 16 + mrow) * DH + k0);
            acc[t] = __builtin_amdgcn_mfma_f32_16x16x32_bf16(a, b, acc[t], 0, 0, 0);
        }
    }

    if (OUTFP8) {
        uchar* my = (uchar*)smem + (tid >> 6) * 16 * CSTB;
        #pragma unroll
        for (int t = 0; t < 8; ++t) {
            int col = t * 16 + mrow;
            float bv = bias ? bias[col] : 0.f;
            #pragma unroll
            for (int r = 0; r < 4; ++r) {
                float v = acc[t][r] + bv;
                if (relu) v = fmaxf(v, 0.f);
                my[(quad * 4 + r) * CSTB + col] = (uchar)f2fp8(v);
            }
        }
        #pragma unroll
        for (int i = 0; i < 4; ++i) {
            int idx = i * 64 + lane;
            int row = idx >> 4;
            int c8 = idx & 15;
            uint2 u = *(const uint2*)(my + row * CSTB + c8 * 8);
            *(uint2*)((uchar*)C + (size_t)(row0 + row) * DH + c8 * 8) = u;
        }
    } else {
        ushort* my = (ushort*)smem + (tid >> 6) * 16 * CST;
        #pragma unroll
        for (int t = 0; t < 8; ++t) {
            int col = t * 16 + mrow;
            float bv = bias ? bias[col] : 0.f;
            #pragma unroll
            for (int r = 0; r < 4; ++r) {
                float v = acc[t][r] + bv;
                if (relu) v = fmaxf(v, 0.f);
                my[(quad * 4 + r) * CST + col] = f2b(v);
            }
        }
        #pragma unroll
        for (int i = 0; i < 4; ++i) {
            int idx = i * 64 + lane;
            int row = idx >> 4;
            int c16 = idx & 15;
            uint4 u = *(const uint4*)(my + row * CST + c16 * 8);
            *(uint4*)((ushort*)C + (size_t)(row0 + row) * DH + c16 * 8) = u;
        }
    }

    if (DOTS) {
        float av[8], dv[8];
        #pragma unroll
        for (int t = 0; t < 8; ++t) {
            av[t] = avs[t * 16 + mrow];
            dv[t] = avd[t * 16 + mrow];
        }
        int orow = row0 + quad * 4;
        #pragma unroll
        for (int r = 0; r < 4; ++r) {
            float ps = 0.f, pd = 0.f;
            #pragma unroll
            for (int t = 0; t < 8; ++t) {
                ps += acc[t][r] * av[t];
                pd += acc[t][r] * dv[t];
            }
            #pragma unroll
            for (int off = 1; off < 16; off <<= 1) {
                ps += __shfl_xor(ps, off);
                pd += __shfl_xor(pd, off);
            }
            if (mrow == 0) {
                asrc[orow + r] = ps;
                adst[orow + r] = pd;
            }
        }
    }
}

// ---------------- fused: GEMM-1 (fp32 x -> bf16 hB) + CSR assembly --------
__launch_bounds__(256)
__global__ void k_buildgemm(const unsigned* __restrict__ tmp, const int* __restrict__ gcur,
                            const int* __restrict__ bsizeP, const int* __restrict__ ploc,
                            int* __restrict__ pstart, ushort* __restrict__ csr,
                            const float* __restrict__ x, const ushort* __restrict__ Wt,
                            const float* __restrict__ b0, ushort* __restrict__ hB) {
    __shared__ char smem[SMEM_BYTES];
    int t = threadIdx.x;
    if (blockIdx.x < GEMMB) {
        gemm_body<true, false, false>(smem, blockIdx.x, x, Wt, b0, hB, 1,
                                      nullptr, nullptr, nullptr, nullptr);
        return;
    }
    int b = blockIdx.x - GEMMB;
    ushort* buf = (ushort*)smem;                      // 8192 ushorts
    int* lcur = (int*)(smem + 16384);                 // NPB ints
    int* sm   = (int*)(smem + 16384 + 1024);          // 256 ints (scan)
    int v = (t < NBK) ? bsizeP[t] : 0;
    sm[t] = v;
    __syncthreads();
    for (int off = 1; off < 256; off <<= 1) {
        int u = (t >= off) ? sm[t - off] : 0;
        __syncthreads();
        sm[t] += u;
        __syncthreads();
    }
    int r0 = sm[b] - bsizeP[b];
    int S = bsizeP[b];                                // multiple of 4
    int n0 = b * NPB, n1 = min(n0 + NPB, NN), nodes = n1 - n0;
    int ne = gcur[b];

    if (S <= 8192) {
        for (int i = t; i < (S >> 1); i += 256) ((unsigned*)buf)[i] = 0;
        __syncthreads();
        if (t < nodes) {
            int lp = ploc[n0 + t];
            pstart[n0 + t] = r0 + lp;
            lcur[t] = lp + 1;
            buf[lp] = (ushort)(n0 + t);               // self-loop first
        }
        __syncthreads();
        for (int e = t; e < ne; e += 256) {
            unsigned u = tmp[(size_t)b * CAPB + e];
            int slot = atomicAdd(&lcur[u >> 16], 1);
            buf[slot] = (ushort)(u & 0xffffu);
        }
        __syncthreads();
        unsigned* dst = (unsigned*)(csr + r0);
        for (int i = t; i < (S >> 1); i += 256) dst[i] = ((unsigned*)buf)[i];
    } else {
        for (int i = t; i < S; i += 256) csr[r0 + i] = 0;
        __syncthreads();
        if (t < nodes) {
            int lp = ploc[n0 + t];
            pstart[n0 + t] = r0 + lp;
            lcur[t] = r0 + lp + 1;
            csr[r0 + lp] = (ushort)(n0 + t);
        }
        __syncthreads();
        for (int e = t; e < ne; e += 256) {
            unsigned u = tmp[(size_t)b * CAPB + e];
            int slot = atomicAdd(&lcur[u >> 16], 1);
            csr[slot] = (ushort)(u & 0xffffu);
        }
    }
}

// ---------------- GEMM + fused attention dots (layers, fp8 out) ----------
__launch_bounds__(256)
__global__ void k_gemmdots(const ushort* __restrict__ hB, const ushort* __restrict__ Wt,
                           uchar* __restrict__ hA,
                           const float* __restrict__ avs, const float* __restrict__ avd,
                           float* __restrict__ asrc, float* __restrict__ adst) {
    __shared__ char smem[SMEM_BYTES];
    gemm_body<false, true, true>(smem, blockIdx.x, hB, Wt, nullptr, hA, 0,
                                 avs, avd, asrc, adst);
}

// ---------------- fused segment softmax + weighted aggregate (fp8 h) -------
__launch_bounds__(256)
__global__ void k_aggr(const uchar* __restrict__ h8, const float* __restrict__ asrc,
                       const float* __restrict__ adst, const int* __restrict__ pstart,
                       const int* __restrict__ deg, const ushort* __restrict__ csr,
                       const float* __restrict__ bias, ushort* __restrict__ hout) {
    int wid = (blockIdx.x * blockDim.x + threadIdx.x) >> 6;
    int lane = threadIdx.x & 63;
    if (wid >= NN) return;
    int start = pstart[wid];
    int cnt = deg[wid] + 1;
    float ad = adst[wid];

    if (cnt <= 64) {
        int s = csr[start + lane];               // pads are 0 (valid index)
        float e = -1e30f;
        if (lane < cnt) {
            float t = asrc[s] + ad;
            e = fmaxf(t, 0.f) + 0.2f * fminf(t, 0.f);
        }
        float m = e;
        #pragma unroll
        for (int off = 32; off; off >>= 1) m = fmaxf(m, __shfl_xor(m, off));
        float w = (lane < cnt) ? __expf(e - m) : 0.f;
        float dsum = w;
        #pragma unroll
        for (int off = 32; off; off >>= 1) dsum += __shfl_xor(dsum, off);

        int g = lane >> 4, fidx = lane & 15;
        float acc[8];
        #pragma unroll
        for (int k = 0; k < 8; ++k) acc[k] = 0.f;

        int steps = (cnt + 3) >> 2;
        const uint2* hp = (const uint2*)h8;      // 16 uint2 per 128B row
        int j = 0;
        for (; j + 3 < steps; j += 4) {
            int   e0 = j * 4 + g,      e1 = e0 + 4,  e2 = e0 + 8,  e3 = e0 + 12;
            float w0 = __shfl(w, e0),  w1 = __shfl(w, e1);
            float w2 = __shfl(w, e2),  w3 = __shfl(w, e3);
            int   s0 = __shfl(s, e0),  s1 = __shfl(s, e1);
            int   s2 = __shfl(s, e2),  s3 = __shfl(s, e3);
            uint2 u0 = hp[(size_t)s0 * 16 + fidx];
            uint2 u1 = hp[(size_t)s1 * 16 + fidx];
            uint2 u2 = hp[(size_t)s2 * 16 + fidx];
            uint2 u3 = hp[(size_t)s3 * 16 + fidx];
            float v[8];
            fp8x4_up(u0.x, v); fp8x4_up(u0.y, v + 4);
            #pragma unroll
            for (int k = 0; k < 8; ++k) acc[k] += w0 * v[k];
            fp8x4_up(u1.x, v); fp8x4_up(u1.y, v + 4);
            #pragma unroll
            for (int k = 0; k < 8; ++k) acc[k] += w1 * v[k];
            fp8x4_up(u2.x, v); fp8x4_up(u2.y, v + 4);
            #pragma unroll
            for (int k = 0; k < 8; ++k) acc[k] += w2 * v[k];
            fp8x4_up(u3.x, v); fp8x4_up(u3.y, v + 4);
            #pragma unroll
            for (int k = 0; k < 8; ++k) acc[k] += w3 * v[k];
        }
        for (; j < steps; ++j) {
            int e0 = j * 4 + g;
            float w0 = __shfl(w, e0);
            int   s0 = __shfl(s, e0);
            uint2 u0 = hp[(size_t)s0 * 16 + fidx];
            float v[8];
            fp8x4_up(u0.x, v); fp8x4_up(u0.y, v + 4);
            #pragma unroll
            for (int k = 0; k < 8; ++k) acc[k] += w0 * v[k];
        }
        #pragma unroll
        for (int k = 0; k < 8; ++k) {
            acc[k] += __shfl_xor(acc[k], 16);
            acc[k] += __shfl_xor(acc[k], 32);
        }
        if (g == 0) {
            float inv = 1.f / (dsum + 1e-16f);
            const float4* bp = (const float4*)bias;
            float4 b0 = bp[fidx * 2], b1 = bp[fidx * 2 + 1];
            uint4 o;
            o.x = pk2(fmaxf(acc[0] * inv + b0.x, 0.f), fmaxf(acc[1] * inv + b0.y, 0.f));
            o.y = pk2(fmaxf(acc[2] * inv + b0.z, 0.f), fmaxf(acc[3] * inv + b0.w, 0.f));
            o.z = pk2(fmaxf(acc[4] * inv + b1.x, 0.f), fmaxf(acc[5] * inv + b1.y, 0.f));
            o.w = pk2(fmaxf(acc[6] * inv + b1.z, 0.f), fmaxf(acc[7] * inv + b1.w, 0.f));
            ((uint4*)hout)[(size_t)wid * 16 + fidx] = o;
        }
        return;
    }

    // generic fallback (deg > 64) — never with this data
    float m = -1e30f;
    for (int i0 = start; i0 < start + cnt; i0 += 64) {
        int i = i0 + lane;
        float e = -1e30f;
        if (i < start + cnt) {
            int s = csr[i];
            float t = asrc[s] + ad;
            e = fmaxf(t, 0.f) + 0.2f * fminf(t, 0.f);
        }
        m = fmaxf(m, e);
    }
    #pragma unroll
    for (int off = 32; off; off >>= 1) m = fmaxf(m, __shfl_xor(m, off));

    float accx = 0.f, accy = 0.f, dsum = 0.f;
    for (int i0 = start; i0 < start + cnt; i0 += 64) {
        int i = i0 + lane;
        int s = 0; float w = 0.f;
        if (i < start + cnt) {
            s = csr[i];
            float t = asrc[s] + ad;
            float e = fmaxf(t, 0.f) + 0.2f * fminf(t, 0.f);
            w = __expf(e - m);
        }
        dsum += w;
        int cl = min(64, start + cnt - i0);
        for (int j = 0; j < cl; ++j) {
            int   sj = __shfl(s, j);
            float wj = __shfl(w, j);
            unsigned us = *(const ushort*)(h8 + (size_t)sj * DH + lane * 2);
            float v[4];
            fp8x4_up(us, v);                      // v[0],v[1] valid
            accx += wj * v[0];
            accy += wj * v[1];
        }
    }
    #pragma unroll
    for (int off = 32; off; off >>= 1) dsum += __shfl_xor(dsum, off);

    float inv = 1.f / (dsum + 1e-16f);
    float ox = fmaxf(accx * inv + bias[lane * 2], 0.f);
    float oy = fmaxf(accy * inv + bias[lane * 2 + 1], 0.f);
    *(unsigned*)(hout + (size_t)wid * DH + lane * 2) = pk2(ox, oy);
}

// ---------------- mean pool (batch sorted, bf16 h, 2 rows in flight) -------
__launch_bounds__(256)
__global__ void k_pool(const ushort* __restrict__ h, const int* __restrict__ batch,
                       float* __restrict__ gsum, int* __restrict__ gcnt) {
    int slot = threadIdx.x >> 7;          // 0 or 1
    int f = threadIdx.x & 127;
    int n0 = blockIdx.x * 64;
    int n1 = min(n0 + 64, NN);
    int first = n0 + slot;
    if (first >= n1) return;
    int g0 = batch[n0], g1 = batch[n1 - 1];
    if (g0 == g1) {                       // fast path: uniform tile (92%)
        float acc = 0.f;
        for (int nd = first; nd < n1; nd += 2)
            acc += b2f(h[(size_t)nd * DH + f]);
        atomicAdd(&gsum[g0 * DH + f], acc);
        if (f == 0 && slot == 0) atomicAdd(&gcnt[g0], n1 - n0);
        return;
    }
    float acc = 0.f; int run = 0;
    int gcur = batch[first];
    for (int nd = first; nd < n1; nd += 2) {
        int g = batch[nd];
        if (g != gcur) {
            atomicAdd(&gsum[gcur * DH + f], acc);
            if (f == 0) atomicAdd(&gcnt[gcur], run);
            acc = 0.f; run = 0; gcur = g;
        }
        acc += b2f(h[(size_t)nd * DH + f]);
        run += 1;
    }
    atomicAdd(&gsum[gcur * DH + f], acc);
    if (f == 0) atomicAdd(&gcnt[gcur], run);
}

// ---------------- final linear [64,128]@[128,10] -> fp32 out ----------------
__global__ void k_final(const float* __restrict__ gsum, const int* __restrict__ gcnt,
                        const float* __restrict__ W1, const float* __restrict__ b1,
                        float* __restrict__ out) {
    int t = threadIdx.x;
    if (t >= NG * 10) return;
    int g = t / 10, o = t % 10;
    float inv = 1.f / fmaxf((float)gcnt[g], 1.f);
    float acc = 0.f;
    for (int f = 0; f < DH; ++f) acc += gsum[g * DH + f] * W1[f * 10 + o];
    out[t] = acc * inv + b1[o];
}

extern "C" void kernel_launch(void* const* d_in, const int* in_sizes, int n_in,
                              void* d_out, int out_size, void* d_ws, size_t ws_size,
                              hipStream_t stream) {
    const float* x       = (const float*)d_in[0];
    const int*   ei      = (const int*)d_in[1];
    const int*   batch   = (const int*)d_in[3];
    const float* W0      = (const float*)d_in[4];
    const float* b0      = (const float*)d_in[5];
    const float* Wc      = (const float*)d_in[6];
    const float* att_src = (const float*)d_in[7];
    const float* att_dst = (const float*)d_in[8];
    const float* bc      = (const float*)d_in[9];
    const float* W1      = (const float*)d_in[10];
    const float* b1      = (const float*)d_in[11];
    float* out = (float*)d_out;

    char* ws = (char*)d_ws;
    size_t off = 0;
    auto alloc = [&](size_t bytes) {
        void* p = ws + off;
        off += (bytes + 255) & ~(size_t)255;
        return p;
    };
    uchar*    hA     = (uchar*)alloc((size_t)NN * DH);        // fp8 e4m3
    ushort*   hB     = (ushort*)alloc((size_t)NN * DH * 2);   // bf16
    ushort*   Wt     = (ushort*)alloc((size_t)4 * DH * DH * 2);
    int*      pstart = (int*)alloc((size_t)NN * 4);
    ushort*   csr    = (ushort*)alloc((size_t)(NE + 4 * NN + 64) * 2);
    unsigned* tmp    = (unsigned*)alloc((size_t)NBK * CAPB * 4);
    float*    asrc   = (float*)alloc(NN * 4);
    float*    adst   = (float*)alloc(NN * 4);
    int*      deg    = (int*)alloc(NN * 4);
    int*      ploc   = (int*)alloc(NN * 4);
    int*      gcur   = (int*)alloc((NBK + 1) * 4);
    int*      bsizeP = (int*)alloc((NBK + 1) * 4);
    float*    gsum   = (float*)alloc(NG * DH * 4);   // gsum+gcnt adjacent
    int*      gcnt   = (int*)alloc(NG * 4);

    hipMemsetAsync(gcur, 0, (NBK + 1) * 4, stream);
    hipMemsetAsync(gsum, 0, NG * DH * 4 + 256, stream);  // covers gcnt too

    k_partwt<<<NPBLK + 256, 256, 0, stream>>>(ei, gcur, tmp, W0, Wc, Wt);
    k_bcount<<<NBK, 256, 0, stream>>>(tmp, gcur, deg, ploc, bsizeP);
    k_buildgemm<<<GEMMB + NBK, 256, 0, stream>>>(tmp, gcur, bsizeP, ploc, pstart, csr,
                                                 x, Wt, b0, hB);

    for (int l = 0; l < 3; ++l) {
        k_gemmdots<<<GEMMB, 256, 0, stream>>>(hB, Wt + (size_t)(l + 1) * DH * DH, hA,
                                              att_src + l * DH, att_dst + l * DH,
                                              asrc, adst);
        k_aggr<<<(NN + 3) / 4, 256, 0, stream>>>(hA, asrc, adst, pstart, deg, csr,
                                                 bc + l * DH, hB);
    }

    k_pool<<<(NN + 63) / 64, 256, 0, stream>>>(hB, batch, gsum, gcnt);
    k_final<<<1, NG * 10, 0, stream>>>(gsum, gcnt, W1, b1, out);
}